// Round 1
// baseline (147.506 us; speedup 1.0000x reference)
//
#include <hip/hip_runtime.h>
#include <stdint.h>
#include <stddef.h>

// ---------------------------------------------------------------------------
// cseft reassociated, W1 folded into U (no qb, final K halved). 5 launches:
//   1. prep:  xb=bf16(x), yb=bf16(y), w1b=bf16(W1) [512,1024] (no transpose),
//             w23t=bf16([W2|W3]^T) [2048,512]
//   2. stage_kv: kvt[2048,4096] = w23t @ yb^T  (rows 0..1023 k-ch, 1024.. v-ch)
//   3. build_u (MFMA): Ut[s*128+d][h*128+dp] =
//              cw[h]*sc * sum_i kvt[1024+h*128+d][s*256+i]*kvt[h*128+dp][s*256+i]
//   4. build_m: M[2048,512] = Ut @ W1  (Bt = w1b row-major, K=1024, bf16 out)
//   5. out[4096,2048] = xb @ M^T  (K=512, fp32 out)
// N=4096 K=512 H=8 Dh=128 nItem=256 nSet=16 hardcoded.
// ---------------------------------------------------------------------------

typedef short short8 __attribute__((ext_vector_type(8)));
typedef float f32x4 __attribute__((ext_vector_type(4)));

#define AS1 __attribute__((address_space(1)))
#define AS3 __attribute__((address_space(3)))

__device__ __forceinline__ void gl_lds16(const void* g, void* l) {
    __builtin_amdgcn_global_load_lds((AS1 void*)(uintptr_t)g, (AS3 void*)l, 16, 0, 0);
}

__device__ __forceinline__ short f2bf(float f) {
    union { float f; unsigned u; } v; v.f = f;
    unsigned r = v.u + 0x7FFFu + ((v.u >> 16) & 1u);
    return (short)(r >> 16);
}

// --- prep: 0..1023 x->xb, 1024..2047 y->yb, 2048..3071 W2/W3->w23t (T),
//     3072..3327 W1->w1b (straight bf16 convert). 3328 blocks x 256 thr.
__global__ __launch_bounds__(256)
void prep(const float* __restrict__ x, const float* __restrict__ y,
          const float* __restrict__ W1, const float* __restrict__ W2,
          const float* __restrict__ W3, short* __restrict__ xb,
          short* __restrict__ yb, short* __restrict__ w1b,
          short* __restrict__ w23t) {
    const int b = blockIdx.x, tid = threadIdx.x;
    if (b < 2048) {
        const float* in = (b < 1024) ? x : y;
        short* o = (b < 1024) ? xb : yb;
        const int i = (b & 1023) * 256 + tid;
        const float4* p = (const float4*)in + (size_t)i * 2;
        float4 a = p[0], c4 = p[1];
        short8 s8;
        s8[0] = f2bf(a.x);  s8[1] = f2bf(a.y);
        s8[2] = f2bf(a.z);  s8[3] = f2bf(a.w);
        s8[4] = f2bf(c4.x); s8[5] = f2bf(c4.y);
        s8[6] = f2bf(c4.z); s8[7] = f2bf(c4.w);
        *((short8*)o + i) = s8;
        return;
    }
    if (b >= 3072) {
        // W1 [512,1024] fp32 -> bf16, row-major (this IS the Bt operand of
        // build_m: Bt[c,p] = W1[c,p]). 256 blocks x 256 thr x 8 elems.
        const int i = (b - 3072) * 256 + tid;
        const float4* p = (const float4*)W1 + (size_t)i * 2;
        float4 a = p[0], c4 = p[1];
        short8 s8;
        s8[0] = f2bf(a.x);  s8[1] = f2bf(a.y);
        s8[2] = f2bf(a.z);  s8[3] = f2bf(a.w);
        s8[4] = f2bf(c4.x); s8[5] = f2bf(c4.y);
        s8[6] = f2bf(c4.z); s8[7] = f2bf(c4.w);
        *((short8*)w1b + i) = s8;
        return;
    }
    __shared__ float t[32][33];
    const int b2 = b - 2048;                     // 0..1023
    const int z = b2 >> 9;                       // 0: W2, 1: W3
    const float* W = z ? W3 : W2;
    short* Wt = w23t + (size_t)z * 1024 * 512;
    const int b3 = b2 & 511;
    const int bx = (b3 & 31) * 32, by = (b3 >> 5) * 32;
    const int tx = tid & 31, ty = tid >> 5;
    #pragma unroll
    for (int j = 0; j < 4; ++j)
        t[ty + j * 8][tx] = W[(size_t)(by + ty + j * 8) * 1024 + bx + tx];
    __syncthreads();
    #pragma unroll
    for (int j = 0; j < 4; ++j)
        Wt[(size_t)(bx + ty + j * 8) * 512 + by + tx] = f2bf(t[tx][ty + j * 8]);
}

// --- generic MFMA tile: C[128x128] = A[.,K] * Bt[.,K]^T --------------------
// 4 waves in 2x2; OUTMODE: 0 = f32 store, 1 = bf16 store, 2 = bf16*scale.
template <int OUTMODE>
__device__ __forceinline__
void gemm_tile(const short* __restrict__ A, int lda,
               const short* __restrict__ Bt, int ldb,
               void* __restrict__ Cout, int ldc, int K,
               int bx, int by, float scale, char* smem) {
    short* sA = (short*)smem;                 // [128][32]
    short* sB = (short*)(smem + 8192);        // [128][32]

    const int tid = threadIdx.x;
    const int wave = tid >> 6, lane = tid & 63;
    const int quad = lane >> 4, ml = lane & 15;
    const int m0 = by * 128, n0 = bx * 128;
    const int wm0 = (wave >> 1) * 64, wn0 = (wave & 1) * 64;
    const int srow = lane >> 2, skoff = (lane & 3) * 8;

    f32x4 acc[4][4];
    #pragma unroll
    for (int i = 0; i < 4; ++i)
        #pragma unroll
        for (int j = 0; j < 4; ++j) {
            acc[i][j][0] = 0.f; acc[i][j][1] = 0.f;
            acc[i][j][2] = 0.f; acc[i][j][3] = 0.f;
        }

    for (int kt = 0; kt < K; kt += 32) {
        #pragma unroll
        for (int ci = 0; ci < 4; ++ci) {
            const int c = wave + ci * 4;
            if (c < 8)
                gl_lds16(A + (size_t)(m0 + c * 16 + srow) * lda + kt + skoff,
                         (char*)sA + c * 1024 + lane * 16);
            else
                gl_lds16(Bt + (size_t)(n0 + (c - 8) * 16 + srow) * ldb + kt + skoff,
                         (char*)sB + (c - 8) * 1024 + lane * 16);
        }
        __syncthreads();   // drains vmcnt for global_load_lds

        short8 af[4], bfr[4];
        #pragma unroll
        for (int mt = 0; mt < 4; ++mt)
            af[mt] = *(const short8*)(sA + (wm0 + mt * 16 + ml) * 32 + quad * 8);
        #pragma unroll
        for (int nt = 0; nt < 4; ++nt)
            bfr[nt] = *(const short8*)(sB + (wn0 + nt * 16 + ml) * 32 + quad * 8);

        #pragma unroll
        for (int mt = 0; mt < 4; ++mt)
            #pragma unroll
            for (int nt = 0; nt < 4; ++nt)
                acc[mt][nt] = __builtin_amdgcn_mfma_f32_16x16x32_bf16(
                    af[mt], bfr[nt], acc[mt][nt], 0, 0, 0);
        __syncthreads();
    }

    // C/D layout: col = lane&15, row = quad*4 + reg
    #pragma unroll
    for (int mt = 0; mt < 4; ++mt)
        #pragma unroll
        for (int nt = 0; nt < 4; ++nt) {
            const int col = n0 + wn0 + nt * 16 + ml;
            #pragma unroll
            for (int r = 0; r < 4; ++r) {
                const int row = m0 + wm0 + mt * 16 + quad * 4 + r;
                float v = acc[mt][nt][r];
                if (OUTMODE == 2) v *= scale;
                if (OUTMODE == 0)
                    ((float*)Cout)[(size_t)row * ldc + col] = v;
                else
                    ((short*)Cout)[(size_t)row * ldc + col] = f2bf(v);
            }
        }
}

// stage_kv: kvt[2048,4096] = w23t @ yb^T : m-tiles 16, n-tiles 32. 512 blocks.
__global__ __launch_bounds__(256)
void stage_kv(const short* __restrict__ yb, const short* __restrict__ w23t,
              short* __restrict__ kvt) {
    __shared__ char smem[16384];
    const int b = blockIdx.x;
    gemm_tile<1>(w23t, 512, yb, 512, kvt, 4096, 512,
                 b & 31, b >> 5, 1.f, smem);
}

// build_u: grid (16,8); Ut tile (s,h) = scale * V_rows @ K_rows^T, K=256.
__global__ __launch_bounds__(256)
void build_u(const short* __restrict__ kvt, const float* __restrict__ cw,
             short* __restrict__ Ut) {
    __shared__ char smem[16384];
    const int s = blockIdx.x, h = blockIdx.y;
    const float scale = cw[h] * (0.08838834764831845f / 256.0f);
    gemm_tile<2>(kvt + (size_t)(1024 + h * 128) * 4096 + s * 256, 4096,  // V: m=d
                 kvt + (size_t)(h * 128) * 4096 + s * 256, 4096,         // K: n=dp
                 Ut + (size_t)(s * 128) * 1024 + h * 128, 1024, 256,
                 0, 0, scale, smem);
}

// build_m: M[2048,512] = Ut @ W1 (Bt = w1b row-major [512,1024]), K=1024.
// grid (4,16) = 64 blocks.
__global__ __launch_bounds__(256)
void build_m(const short* __restrict__ Ut, const short* __restrict__ w1b,
             short* __restrict__ M) {
    __shared__ char smem[16384];
    gemm_tile<1>(Ut, 1024, w1b, 1024, M, 512, 1024,
                 blockIdx.x, blockIdx.y, 1.f, smem);
}

// out[4096,2048] = xb @ M^T, fp32, K=512. grid (16,32).
__global__ __launch_bounds__(256)
void gemm_out(const short* __restrict__ xb, const short* __restrict__ M,
              float* __restrict__ out) {
    __shared__ char smem[16384];
    gemm_tile<0>(xb, 512, M, 512, out, 2048, 512,
                 blockIdx.x, blockIdx.y, 1.f, smem);
}

extern "C" void kernel_launch(void* const* d_in, const int* in_sizes, int n_in,
                              void* d_out, int out_size, void* d_ws, size_t ws_size,
                              hipStream_t stream) {
    const float* x  = (const float*)d_in[0];  // [4096, 512]
    const float* y  = (const float*)d_in[1];  // [4096, 512]
    const float* W1 = (const float*)d_in[2];  // [512, 1024]
    const float* W2 = (const float*)d_in[3];
    const float* W3 = (const float*)d_in[4];
    const float* cw = (const float*)d_in[5];  // [8]
    float* out = (float*)d_out;               // [4096, 16, 128]

    short* xb   = (short*)d_ws;                       // 4096*512
    short* yb   = xb   + (size_t)4096 * 512;          // 4096*512
    short* w23t = yb   + (size_t)4096 * 512;          // 2048*512 (transposed)
    short* w1b  = w23t + (size_t)2048 * 512;          // 512*1024 (row-major)
    short* kvt  = w1b  + (size_t)512 * 1024;          // 2048*4096
    short* Ut   = kvt  + (size_t)2048 * 4096;         // 2048*1024
    short* M    = Ut   + (size_t)2048 * 1024;         // 2048*512

    prep<<<3328, 256, 0, stream>>>(x, y, W1, W2, W3, xb, yb, w1b, w23t);
    stage_kv<<<512, 256, 0, stream>>>(yb, w23t, kvt);
    build_u<<<dim3(16, 8), 256, 0, stream>>>(kvt, cw, Ut);
    build_m<<<dim3(4, 16), 256, 0, stream>>>(Ut, w1b, M);
    gemm_out<<<dim3(16, 32), 256, 0, stream>>>(xb, M, out);
}

// Round 2
// 138.635 us; speedup vs baseline: 1.0640x; 1.0640x over previous
//
#include <hip/hip_runtime.h>
#include <stdint.h>
#include <stddef.h>

// ---------------------------------------------------------------------------
// cseft reassociated, W1 folded into U (no qb, final K halved). 5 launches:
//   1. prep:  xb=bf16(x), yb=bf16(y), w1b=bf16(W1) [512,1024] (no transpose),
//             w23t=bf16([W2|W3]^T) [2048,512]
//   2. stage_kv: kvt[2048,4096] = w23t @ yb^T  (rows 0..1023 k-ch, 1024.. v-ch)
//   3. build_u (MFMA): Ut[s*128+d][h*128+dp] =
//              cw[h]*sc * sum_i kvt[1024+h*128+d][s*256+i]*kvt[h*128+dp][s*256+i]
//   4. build_m: M[2048,512] = Ut @ W1  (Bt = w1b row-major, K=1024, bf16 out)
//   5. out[4096,2048] = xb @ M^T  (K=512, fp32 out)
// N=4096 K=512 H=8 Dh=128 nItem=256 nSet=16 hardcoded.
//
// gemm_tile uses the T3 minimum 2-phase pipeline: double-buffered LDS,
// prefetch tile t+1 via global_load_lds BEFORE computing tile t, ONE
// __syncthreads() per K-step at the END (its implicit vmcnt(0)/lgkmcnt(0)
// drain lands after the MFMAs -> load latency hidden under compute).
// ---------------------------------------------------------------------------

typedef short short8 __attribute__((ext_vector_type(8)));
typedef float f32x4 __attribute__((ext_vector_type(4)));

#define AS1 __attribute__((address_space(1)))
#define AS3 __attribute__((address_space(3)))

__device__ __forceinline__ void gl_lds16(const void* g, void* l) {
    __builtin_amdgcn_global_load_lds((AS1 void*)(uintptr_t)g, (AS3 void*)l, 16, 0, 0);
}

__device__ __forceinline__ short f2bf(float f) {
    union { float f; unsigned u; } v; v.f = f;
    unsigned r = v.u + 0x7FFFu + ((v.u >> 16) & 1u);
    return (short)(r >> 16);
}

// --- prep: 0..1023 x->xb, 1024..2047 y->yb, 2048..3071 W2/W3->w23t (T),
//     3072..3327 W1->w1b (straight bf16 convert). 3328 blocks x 256 thr.
__global__ __launch_bounds__(256)
void prep(const float* __restrict__ x, const float* __restrict__ y,
          const float* __restrict__ W1, const float* __restrict__ W2,
          const float* __restrict__ W3, short* __restrict__ xb,
          short* __restrict__ yb, short* __restrict__ w1b,
          short* __restrict__ w23t) {
    const int b = blockIdx.x, tid = threadIdx.x;
    if (b < 2048) {
        const float* in = (b < 1024) ? x : y;
        short* o = (b < 1024) ? xb : yb;
        const int i = (b & 1023) * 256 + tid;
        const float4* p = (const float4*)in + (size_t)i * 2;
        float4 a = p[0], c4 = p[1];
        short8 s8;
        s8[0] = f2bf(a.x);  s8[1] = f2bf(a.y);
        s8[2] = f2bf(a.z);  s8[3] = f2bf(a.w);
        s8[4] = f2bf(c4.x); s8[5] = f2bf(c4.y);
        s8[6] = f2bf(c4.z); s8[7] = f2bf(c4.w);
        *((short8*)o + i) = s8;
        return;
    }
    if (b >= 3072) {
        // W1 [512,1024] fp32 -> bf16, row-major (this IS the Bt operand of
        // build_m: Bt[c,p] = W1[c,p]). 256 blocks x 256 thr x 8 elems.
        const int i = (b - 3072) * 256 + tid;
        const float4* p = (const float4*)W1 + (size_t)i * 2;
        float4 a = p[0], c4 = p[1];
        short8 s8;
        s8[0] = f2bf(a.x);  s8[1] = f2bf(a.y);
        s8[2] = f2bf(a.z);  s8[3] = f2bf(a.w);
        s8[4] = f2bf(c4.x); s8[5] = f2bf(c4.y);
        s8[6] = f2bf(c4.z); s8[7] = f2bf(c4.w);
        *((short8*)w1b + i) = s8;
        return;
    }
    __shared__ float t[32][33];
    const int b2 = b - 2048;                     // 0..1023
    const int z = b2 >> 9;                       // 0: W2, 1: W3
    const float* W = z ? W3 : W2;
    short* Wt = w23t + (size_t)z * 1024 * 512;
    const int b3 = b2 & 511;
    const int bx = (b3 & 31) * 32, by = (b3 >> 5) * 32;
    const int tx = tid & 31, ty = tid >> 5;
    #pragma unroll
    for (int j = 0; j < 4; ++j)
        t[ty + j * 8][tx] = W[(size_t)(by + ty + j * 8) * 1024 + bx + tx];
    __syncthreads();
    #pragma unroll
    for (int j = 0; j < 4; ++j)
        Wt[(size_t)(bx + ty + j * 8) * 512 + by + tx] = f2bf(t[tx][ty + j * 8]);
}

// --- generic MFMA tile: C[128x128] = A[.,K] * Bt[.,K]^T --------------------
// 4 waves in 2x2; OUTMODE: 0 = f32 store, 1 = bf16 store, 2 = bf16*scale.
// Double-buffered (smem = 2 x 16 KB), 1 barrier per K-step.
template <int OUTMODE>
__device__ __forceinline__
void gemm_tile(const short* __restrict__ A, int lda,
               const short* __restrict__ Bt, int ldb,
               void* __restrict__ Cout, int ldc, int K,
               int bx, int by, float scale, char* smem) {
    const int tid = threadIdx.x;
    const int wave = tid >> 6, lane = tid & 63;
    const int quad = lane >> 4, ml = lane & 15;
    const int m0 = by * 128, n0 = bx * 128;
    const int wm0 = (wave >> 1) * 64, wn0 = (wave & 1) * 64;
    const int srow = lane >> 2, skoff = (lane & 3) * 8;

    f32x4 acc[4][4];
    #pragma unroll
    for (int i = 0; i < 4; ++i)
        #pragma unroll
        for (int j = 0; j < 4; ++j) {
            acc[i][j][0] = 0.f; acc[i][j][1] = 0.f;
            acc[i][j][2] = 0.f; acc[i][j][3] = 0.f;
        }

    // stage one 128x32 A-tile and 128x32 B-tile into buffer `sbuf`
    auto STAGE = [&](char* sbuf, int kt) {
        #pragma unroll
        for (int ci = 0; ci < 4; ++ci) {
            const int c = wave + ci * 4;
            if (c < 8)
                gl_lds16(A + (size_t)(m0 + c * 16 + srow) * lda + kt + skoff,
                         sbuf + c * 1024 + lane * 16);
            else
                gl_lds16(Bt + (size_t)(n0 + (c - 8) * 16 + srow) * ldb + kt + skoff,
                         sbuf + 8192 + (c - 8) * 1024 + lane * 16);
        }
    };

    const int nt = K >> 5;
    STAGE(smem, 0);
    __syncthreads();              // drain vmcnt(0): buf0 ready

    int cur = 0;
    for (int t = 0; t < nt; ++t) {
        char* sbuf = smem + cur * 16384;
        if (t + 1 < nt)
            STAGE(smem + (cur ^ 1) * 16384, (t + 1) * 32);  // prefetch next

        const short* sA = (const short*)sbuf;
        const short* sB = (const short*)(sbuf + 8192);
        short8 af[4], bfr[4];
        #pragma unroll
        for (int mt = 0; mt < 4; ++mt)
            af[mt] = *(const short8*)(sA + (wm0 + mt * 16 + ml) * 32 + quad * 8);
        #pragma unroll
        for (int nt2 = 0; nt2 < 4; ++nt2)
            bfr[nt2] = *(const short8*)(sB + (wn0 + nt2 * 16 + ml) * 32 + quad * 8);

        #pragma unroll
        for (int mt = 0; mt < 4; ++mt)
            #pragma unroll
            for (int nt2 = 0; nt2 < 4; ++nt2)
                acc[mt][nt2] = __builtin_amdgcn_mfma_f32_16x16x32_bf16(
                    af[mt], bfr[nt2], acc[mt][nt2], 0, 0, 0);

        __syncthreads();  // drains vmcnt(0): next buf ready; all waves done
                          // reading sbuf -> safe to overwrite next step
        cur ^= 1;
    }

    // C/D layout: col = lane&15, row = quad*4 + reg
    #pragma unroll
    for (int mt = 0; mt < 4; ++mt)
        #pragma unroll
        for (int nt2 = 0; nt2 < 4; ++nt2) {
            const int col = n0 + wn0 + nt2 * 16 + ml;
            #pragma unroll
            for (int r = 0; r < 4; ++r) {
                const int row = m0 + wm0 + mt * 16 + quad * 4 + r;
                float v = acc[mt][nt2][r];
                if (OUTMODE == 2) v *= scale;
                if (OUTMODE == 0)
                    ((float*)Cout)[(size_t)row * ldc + col] = v;
                else
                    ((short*)Cout)[(size_t)row * ldc + col] = f2bf(v);
            }
        }
}

// stage_kv: kvt[2048,4096] = w23t @ yb^T : m-tiles 16, n-tiles 32. 512 blocks.
__global__ __launch_bounds__(256)
void stage_kv(const short* __restrict__ yb, const short* __restrict__ w23t,
              short* __restrict__ kvt) {
    __shared__ char smem[32768];
    const int b = blockIdx.x;
    gemm_tile<1>(w23t, 512, yb, 512, kvt, 4096, 512,
                 b & 31, b >> 5, 1.f, smem);
}

// build_u: grid (16,8); Ut tile (s,h) = scale * V_rows @ K_rows^T, K=256.
__global__ __launch_bounds__(256)
void build_u(const short* __restrict__ kvt, const float* __restrict__ cw,
             short* __restrict__ Ut) {
    __shared__ char smem[32768];
    const int s = blockIdx.x, h = blockIdx.y;
    const float scale = cw[h] * (0.08838834764831845f / 256.0f);
    gemm_tile<2>(kvt + (size_t)(1024 + h * 128) * 4096 + s * 256, 4096,  // V: m=d
                 kvt + (size_t)(h * 128) * 4096 + s * 256, 4096,         // K: n=dp
                 Ut + (size_t)(s * 128) * 1024 + h * 128, 1024, 256,
                 0, 0, scale, smem);
}

// build_m: M[2048,512] = Ut @ W1 (Bt = w1b row-major [512,1024]), K=1024.
// grid (4,16) = 64 blocks.
__global__ __launch_bounds__(256)
void build_m(const short* __restrict__ Ut, const short* __restrict__ w1b,
             short* __restrict__ M) {
    __shared__ char smem[32768];
    gemm_tile<1>(Ut, 1024, w1b, 1024, M, 512, 1024,
                 blockIdx.x, blockIdx.y, 1.f, smem);
}

// out[4096,2048] = xb @ M^T, fp32, K=512. grid (16,32).
__global__ __launch_bounds__(256)
void gemm_out(const short* __restrict__ xb, const short* __restrict__ M,
              float* __restrict__ out) {
    __shared__ char smem[32768];
    gemm_tile<0>(xb, 512, M, 512, out, 2048, 512,
                 blockIdx.x, blockIdx.y, 1.f, smem);
}

extern "C" void kernel_launch(void* const* d_in, const int* in_sizes, int n_in,
                              void* d_out, int out_size, void* d_ws, size_t ws_size,
                              hipStream_t stream) {
    const float* x  = (const float*)d_in[0];  // [4096, 512]
    const float* y  = (const float*)d_in[1];  // [4096, 512]
    const float* W1 = (const float*)d_in[2];  // [512, 1024]
    const float* W2 = (const float*)d_in[3];
    const float* W3 = (const float*)d_in[4];
    const float* cw = (const float*)d_in[5];  // [8]
    float* out = (float*)d_out;               // [4096, 16, 128]

    short* xb   = (short*)d_ws;                       // 4096*512
    short* yb   = xb   + (size_t)4096 * 512;          // 4096*512
    short* w23t = yb   + (size_t)4096 * 512;          // 2048*512 (transposed)
    short* w1b  = w23t + (size_t)2048 * 512;          // 512*1024 (row-major)
    short* kvt  = w1b  + (size_t)512 * 1024;          // 2048*4096
    short* Ut   = kvt  + (size_t)2048 * 4096;         // 2048*1024
    short* M    = Ut   + (size_t)2048 * 1024;         // 2048*512

    prep<<<3328, 256, 0, stream>>>(x, y, W1, W2, W3, xb, yb, w1b, w23t);
    stage_kv<<<512, 256, 0, stream>>>(yb, w23t, kvt);
    build_u<<<dim3(16, 8), 256, 0, stream>>>(kvt, cw, Ut);
    build_m<<<dim3(4, 16), 256, 0, stream>>>(Ut, w1b, M);
    gemm_out<<<dim3(16, 32), 256, 0, stream>>>(xb, M, out);
}

// Round 4
// 137.781 us; speedup vs baseline: 1.0706x; 1.0062x over previous
//
#include <hip/hip_runtime.h>
#include <stdint.h>
#include <stddef.h>

// ---------------------------------------------------------------------------
// cseft reassociated, W1 folded into U (no qb, final K halved). 5 launches:
//   1. prep:  xb=bf16(x), yb=bf16(y), w1b=bf16(W1) [512,1024] (no transpose),
//             w23t=bf16([W2|W3]^T) [2048,512]
//   2. stage_kv: kvt[2048,4096] = w23t @ yb^T  (rows 0..1023 k-ch, 1024.. v-ch)
//   3. build_u (MFMA): Ut[s*128+d][h*128+dp] =
//              cw[h]*sc * sum_i kvt[1024+h*128+d][s*256+i]*kvt[h*128+dp][s*256+i]
//   4. build_m: M[2048,512] = Ut @ W1  (Bt = w1b row-major, K=1024, bf16 out)
//   5. out[4096,2048] = xb @ M^T  (K=512, fp32 out)
// N=4096 K=512 H=8 Dh=128 nItem=256 nSet=16 hardcoded.
//
// gemm_tile: T3+T4 pipeline — THREE LDS buffers (3x16KB), prefetch depth 2,
// counted `s_waitcnt vmcnt(4)` + raw s_barrier per K-step (never drain the
// in-flight prefetch; m135 oldest-first vmcnt semantics). Targets the
// latency-bound regime: per-step exposed load latency ~500-900cy with the
// round-2 depth-1 dbuf, since __syncthreads drained vmcnt(0).
//
// NOTE (round 3 post-mortem): single cooperative kernel with grid.sync()
// FAILED correctness — plain stores are not cross-XCD coherent inside one
// kernel (per-XCD L2 writeback; grid.sync lacks agent-scope wb/inv), and/or
// cooperative launch vs harness graph capture. Separate launches are the
// correct coherence boundary. Do not re-fuse without device-scope fences.
// ---------------------------------------------------------------------------

typedef short short8 __attribute__((ext_vector_type(8)));
typedef float f32x4 __attribute__((ext_vector_type(4)));

#define AS1 __attribute__((address_space(1)))
#define AS3 __attribute__((address_space(3)))

__device__ __forceinline__ void gl_lds16(const void* g, void* l) {
    __builtin_amdgcn_global_load_lds((AS1 void*)(uintptr_t)g, (AS3 void*)l, 16, 0, 0);
}

__device__ __forceinline__ short f2bf(float f) {
    union { float f; unsigned u; } v; v.f = f;
    unsigned r = v.u + 0x7FFFu + ((v.u >> 16) & 1u);
    return (short)(r >> 16);
}

// --- prep: 0..1023 x->xb, 1024..2047 y->yb, 2048..3071 W2/W3->w23t (T),
//     3072..3327 W1->w1b (straight bf16 convert). 3328 blocks x 256 thr.
__global__ __launch_bounds__(256)
void prep(const float* __restrict__ x, const float* __restrict__ y,
          const float* __restrict__ W1, const float* __restrict__ W2,
          const float* __restrict__ W3, short* __restrict__ xb,
          short* __restrict__ yb, short* __restrict__ w1b,
          short* __restrict__ w23t) {
    const int b = blockIdx.x, tid = threadIdx.x;
    if (b < 2048) {
        const float* in = (b < 1024) ? x : y;
        short* o = (b < 1024) ? xb : yb;
        const int i = (b & 1023) * 256 + tid;
        const float4* p = (const float4*)in + (size_t)i * 2;
        float4 a = p[0], c4 = p[1];
        short8 s8;
        s8[0] = f2bf(a.x);  s8[1] = f2bf(a.y);
        s8[2] = f2bf(a.z);  s8[3] = f2bf(a.w);
        s8[4] = f2bf(c4.x); s8[5] = f2bf(c4.y);
        s8[6] = f2bf(c4.z); s8[7] = f2bf(c4.w);
        *((short8*)o + i) = s8;
        return;
    }
    if (b >= 3072) {
        // W1 [512,1024] fp32 -> bf16, row-major (Bt operand of build_m).
        const int i = (b - 3072) * 256 + tid;
        const float4* p = (const float4*)W1 + (size_t)i * 2;
        float4 a = p[0], c4 = p[1];
        short8 s8;
        s8[0] = f2bf(a.x);  s8[1] = f2bf(a.y);
        s8[2] = f2bf(a.z);  s8[3] = f2bf(a.w);
        s8[4] = f2bf(c4.x); s8[5] = f2bf(c4.y);
        s8[6] = f2bf(c4.z); s8[7] = f2bf(c4.w);
        *((short8*)w1b + i) = s8;
        return;
    }
    __shared__ float t[32][33];
    const int b2 = b - 2048;                     // 0..1023
    const int z = b2 >> 9;                       // 0: W2, 1: W3
    const float* W = z ? W3 : W2;
    short* Wt = w23t + (size_t)z * 1024 * 512;
    const int b3 = b2 & 511;
    const int bx = (b3 & 31) * 32, by = (b3 >> 5) * 32;
    const int tx = tid & 31, ty = tid >> 5;
    #pragma unroll
    for (int j = 0; j < 4; ++j)
        t[ty + j * 8][tx] = W[(size_t)(by + ty + j * 8) * 1024 + bx + tx];
    __syncthreads();
    #pragma unroll
    for (int j = 0; j < 4; ++j)
        Wt[(size_t)(bx + ty + j * 8) * 512 + by + tx] = f2bf(t[tx][ty + j * 8]);
}

// --- generic MFMA tile: C[128x128] = A[.,K] * Bt[.,K]^T --------------------
// 4 waves in 2x2; OUTMODE: 0 = f32 store, 1 = bf16 store, 2 = bf16*scale.
// 3-buffer pipeline, prefetch depth 2, counted vmcnt, raw s_barrier.
// Each STAGE issues 4 global_load_lds per thread (A 8KB + B 8KB per tile).
// Invariants per iter t:
//   - compute reads buf[t%3] (its loads completed: waited last iter)
//   - STAGE writes buf[(t+2)%3], last read at iter t-1, sealed by barrier
//   - wait vmcnt(4): the 4 oldest (t+1's) done, 4 newest (t+2's) in flight
template <int OUTMODE>
__device__ __forceinline__
void gemm_tile(const short* __restrict__ A, int lda,
               const short* __restrict__ Bt, int ldb,
               void* __restrict__ Cout, int ldc, int K,
               int bx, int by, float scale, char* smem) {
    const int tid = threadIdx.x;
    const int wave = tid >> 6, lane = tid & 63;
    const int quad = lane >> 4, ml = lane & 15;
    const int m0 = by * 128, n0 = bx * 128;
    const int wm0 = (wave >> 1) * 64, wn0 = (wave & 1) * 64;
    const int srow = lane >> 2, skoff = (lane & 3) * 8;

    f32x4 acc[4][4];
    #pragma unroll
    for (int i = 0; i < 4; ++i)
        #pragma unroll
        for (int j = 0; j < 4; ++j) {
            acc[i][j][0] = 0.f; acc[i][j][1] = 0.f;
            acc[i][j][2] = 0.f; acc[i][j][3] = 0.f;
        }

    auto STAGE = [&](char* sbuf, int kt) {
        #pragma unroll
        for (int ci = 0; ci < 4; ++ci) {
            const int c = wave + ci * 4;
            if (c < 8)
                gl_lds16(A + (size_t)(m0 + c * 16 + srow) * lda + kt + skoff,
                         sbuf + c * 1024 + lane * 16);
            else
                gl_lds16(Bt + (size_t)(n0 + (c - 8) * 16 + srow) * ldb + kt + skoff,
                         sbuf + 8192 + (c - 8) * 1024 + lane * 16);
        }
    };

    const int nt = K >> 5;                 // >= 8 at every call site
    STAGE(smem, 0);
    STAGE(smem + 16384, 32);
    // buf0 ready when only buf1's 4 loads remain in flight
    asm volatile("s_waitcnt vmcnt(4)" ::: "memory");
    __builtin_amdgcn_s_barrier();

    for (int t = 0; t < nt; ++t) {
        char* sbuf = smem + (t % 3) * 16384;
        if (t + 2 < nt)
            STAGE(smem + ((t + 2) % 3) * 16384, (t + 2) * 32);

        const short* sA = (const short*)sbuf;
        const short* sB = (const short*)(sbuf + 8192);
        short8 af[4], bfr[4];
        #pragma unroll
        for (int mt = 0; mt < 4; ++mt)
            af[mt] = *(const short8*)(sA + (wm0 + mt * 16 + ml) * 32 + quad * 8);
        #pragma unroll
        for (int nt2 = 0; nt2 < 4; ++nt2)
            bfr[nt2] = *(const short8*)(sB + (wn0 + nt2 * 16 + ml) * 32 + quad * 8);

        #pragma unroll
        for (int mt = 0; mt < 4; ++mt)
            #pragma unroll
            for (int nt2 = 0; nt2 < 4; ++nt2)
                acc[mt][nt2] = __builtin_amdgcn_mfma_f32_16x16x32_bf16(
                    af[mt], bfr[nt2], acc[mt][nt2], 0, 0, 0);

        // next buffer's loads must have landed; keep the prefetch in flight
        if (t + 2 < nt)
            asm volatile("s_waitcnt vmcnt(4)" ::: "memory");
        else
            asm volatile("s_waitcnt vmcnt(0)" ::: "memory");
        __builtin_amdgcn_s_barrier();
    }

    // C/D layout: col = lane&15, row = quad*4 + reg
    #pragma unroll
    for (int mt = 0; mt < 4; ++mt)
        #pragma unroll
        for (int nt2 = 0; nt2 < 4; ++nt2) {
            const int col = n0 + wn0 + nt2 * 16 + ml;
            #pragma unroll
            for (int r = 0; r < 4; ++r) {
                const int row = m0 + wm0 + mt * 16 + quad * 4 + r;
                float v = acc[mt][nt2][r];
                if (OUTMODE == 2) v *= scale;
                if (OUTMODE == 0)
                    ((float*)Cout)[(size_t)row * ldc + col] = v;
                else
                    ((short*)Cout)[(size_t)row * ldc + col] = f2bf(v);
            }
        }
}

// stage_kv: kvt[2048,4096] = w23t @ yb^T : m-tiles 16, n-tiles 32. 512 blocks.
__global__ __launch_bounds__(256)
void stage_kv(const short* __restrict__ yb, const short* __restrict__ w23t,
              short* __restrict__ kvt) {
    __shared__ char smem[49152];
    const int b = blockIdx.x;
    gemm_tile<1>(w23t, 512, yb, 512, kvt, 4096, 512,
                 b & 31, b >> 5, 1.f, smem);
}

// build_u: grid (16,8); Ut tile (s,h) = scale * V_rows @ K_rows^T, K=256.
__global__ __launch_bounds__(256)
void build_u(const short* __restrict__ kvt, const float* __restrict__ cw,
             short* __restrict__ Ut) {
    __shared__ char smem[49152];
    const int s = blockIdx.x, h = blockIdx.y;
    const float scale = cw[h] * (0.08838834764831845f / 256.0f);
    gemm_tile<2>(kvt + (size_t)(1024 + h * 128) * 4096 + s * 256, 4096,  // V: m=d
                 kvt + (size_t)(h * 128) * 4096 + s * 256, 4096,         // K: n=dp
                 Ut + (size_t)(s * 128) * 1024 + h * 128, 1024, 256,
                 0, 0, scale, smem);
}

// build_m: M[2048,512] = Ut @ W1 (Bt = w1b row-major [512,1024]), K=1024.
// grid (4,16) = 64 blocks.
__global__ __launch_bounds__(256)
void build_m(const short* __restrict__ Ut, const short* __restrict__ w1b,
             short* __restrict__ M) {
    __shared__ char smem[49152];
    gemm_tile<1>(Ut, 1024, w1b, 1024, M, 512, 1024,
                 blockIdx.x, blockIdx.y, 1.f, smem);
}

// out[4096,2048] = xb @ M^T, fp32, K=512. grid (16,32).
__global__ __launch_bounds__(256)
void gemm_out(const short* __restrict__ xb, const short* __restrict__ M,
              float* __restrict__ out) {
    __shared__ char smem[49152];
    gemm_tile<0>(xb, 512, M, 512, out, 2048, 512,
                 blockIdx.x, blockIdx.y, 1.f, smem);
}

extern "C" void kernel_launch(void* const* d_in, const int* in_sizes, int n_in,
                              void* d_out, int out_size, void* d_ws, size_t ws_size,
                              hipStream_t stream) {
    const float* x  = (const float*)d_in[0];  // [4096, 512]
    const float* y  = (const float*)d_in[1];  // [4096, 512]
    const float* W1 = (const float*)d_in[2];  // [512, 1024]
    const float* W2 = (const float*)d_in[3];
    const float* W3 = (const float*)d_in[4];
    const float* cw = (const float*)d_in[5];  // [8]
    float* out = (float*)d_out;               // [4096, 16, 128]

    short* xb   = (short*)d_ws;                       // 4096*512
    short* yb   = xb   + (size_t)4096 * 512;          // 4096*512
    short* w23t = yb   + (size_t)4096 * 512;          // 2048*512 (transposed)
    short* w1b  = w23t + (size_t)2048 * 512;          // 512*1024 (row-major)
    short* kvt  = w1b  + (size_t)512 * 1024;          // 2048*4096
    short* Ut   = kvt  + (size_t)2048 * 4096;         // 2048*1024
    short* M    = Ut   + (size_t)2048 * 1024;         // 2048*512

    prep<<<3328, 256, 0, stream>>>(x, y, W1, W2, W3, xb, yb, w1b, w23t);
    stage_kv<<<512, 256, 0, stream>>>(yb, w23t, kvt);
    build_u<<<dim3(16, 8), 256, 0, stream>>>(kvt, cw, Ut);
    build_m<<<dim3(4, 16), 256, 0, stream>>>(Ut, w1b, M);
    gemm_out<<<dim3(16, 32), 256, 0, stream>>>(xb, M, out);
}

// Round 6
// 129.386 us; speedup vs baseline: 1.1400x; 1.0649x over previous
//
#include <hip/hip_runtime.h>
#include <stdint.h>
#include <stddef.h>

// ---------------------------------------------------------------------------
// cseft reassociated, W1 folded into U. 5 launches (verified-safe skeleton):
//   1. prep:  xb=bf16(x), yb=bf16(y), w1b=bf16(W1) [512,1024],
//             w23t=bf16([W2|W3]^T) [2048,512]
//   2. stage_kv: kvt[2048,4096] = w23t @ yb^T
//   3. build_u:  Ut[s*128+d][h*128+dp] = cw[h]*sc * V_s @ K_s^T (K=256)
//   4. build_m:  M[2048,512] = Ut @ W1  (K=1024, bf16)
//   5. gemm_out: out[4096,2048] = xb @ M^T  (K=512, fp32)
// N=4096 K=512 H=8 Dh=128 nItem=256 nSet=16 hardcoded.
//
// gemm_tile v3: BK=64 (128B staging segments = full cache lines, 2x fetch
// efficiency vs BK=32's 64B; steps halved), double-buffered 2x32KB LDS, one
// __syncthreads per K-step (R2-proven sync). LDS rows are 128B so ds_read
// would be 16-way bank-conflicted -> T2 XOR swizzle, applied as rule #21
// requires with global_load_lds: LINEAR lds dest + pre-swizzled GLOBAL source
// chunk (ch^rl) + same XOR on the ds_read address (involution both sides).
//
// NOTE: single-kernel fusion attempts FAILED twice (R3 coop: never ran under
// graph capture; R5 sw-barrier: first run correct, replay diverged -> agent
// __threadfence does not invalidate per-XCD L2 on gfx950). Kernel boundaries
// are the only verified cross-XCD coherence points. Do not re-fuse without
// explicit buffer_wbl2/buffer_inv and a fresh correctness round.
// ---------------------------------------------------------------------------

typedef short short8 __attribute__((ext_vector_type(8)));
typedef float f32x4 __attribute__((ext_vector_type(4)));

#define AS1 __attribute__((address_space(1)))
#define AS3 __attribute__((address_space(3)))

__device__ __forceinline__ void gl_lds16(const void* g, void* l) {
    __builtin_amdgcn_global_load_lds((AS1 void*)(uintptr_t)g, (AS3 void*)l, 16, 0, 0);
}

__device__ __forceinline__ short f2bf(float f) {
    union { float f; unsigned u; } v; v.f = f;
    unsigned r = v.u + 0x7FFFu + ((v.u >> 16) & 1u);
    return (short)(r >> 16);
}

// --- prep: 0..1023 x->xb, 1024..2047 y->yb, 2048..3071 W2/W3->w23t (T),
//     3072..3327 W1->w1b (straight bf16 convert). 3328 blocks x 256 thr.
__global__ __launch_bounds__(256)
void prep(const float* __restrict__ x, const float* __restrict__ y,
          const float* __restrict__ W1, const float* __restrict__ W2,
          const float* __restrict__ W3, short* __restrict__ xb,
          short* __restrict__ yb, short* __restrict__ w1b,
          short* __restrict__ w23t) {
    const int b = blockIdx.x, tid = threadIdx.x;
    if (b < 2048) {
        const float* in = (b < 1024) ? x : y;
        short* o = (b < 1024) ? xb : yb;
        const int i = (b & 1023) * 256 + tid;
        const float4* p = (const float4*)in + (size_t)i * 2;
        float4 a = p[0], c4 = p[1];
        short8 s8;
        s8[0] = f2bf(a.x);  s8[1] = f2bf(a.y);
        s8[2] = f2bf(a.z);  s8[3] = f2bf(a.w);
        s8[4] = f2bf(c4.x); s8[5] = f2bf(c4.y);
        s8[6] = f2bf(c4.z); s8[7] = f2bf(c4.w);
        *((short8*)o + i) = s8;
        return;
    }
    if (b >= 3072) {
        const int i = (b - 3072) * 256 + tid;
        const float4* p = (const float4*)W1 + (size_t)i * 2;
        float4 a = p[0], c4 = p[1];
        short8 s8;
        s8[0] = f2bf(a.x);  s8[1] = f2bf(a.y);
        s8[2] = f2bf(a.z);  s8[3] = f2bf(a.w);
        s8[4] = f2bf(c4.x); s8[5] = f2bf(c4.y);
        s8[6] = f2bf(c4.z); s8[7] = f2bf(c4.w);
        *((short8*)w1b + i) = s8;
        return;
    }
    __shared__ float t[32][33];
    const int b2 = b - 2048;                     // 0..1023
    const int z = b2 >> 9;                       // 0: W2, 1: W3
    const float* W = z ? W3 : W2;
    short* Wt = w23t + (size_t)z * 1024 * 512;
    const int b3 = b2 & 511;
    const int bx = (b3 & 31) * 32, by = (b3 >> 5) * 32;
    const int tx = tid & 31, ty = tid >> 5;
    #pragma unroll
    for (int j = 0; j < 4; ++j)
        t[ty + j * 8][tx] = W[(size_t)(by + ty + j * 8) * 1024 + bx + tx];
    __syncthreads();
    #pragma unroll
    for (int j = 0; j < 4; ++j)
        Wt[(size_t)(bx + ty + j * 8) * 512 + by + tx] = f2bf(t[tx][ty + j * 8]);
}

// --- generic MFMA tile: C[128x128] = A[.,K] * Bt[.,K]^T --------------------
// 4 waves 2x2; OUTMODE: 0 = f32 store, 1 = bf16 store, 2 = bf16*scale.
// BK=64, dbuf 2x32KB, 1 __syncthreads per step, XOR-swizzled LDS (T2).
// Buffer layout: [A 128 rows x 128B][B 128 rows x 128B]; LDS holds global
// chunk (row, c^(row&7)) at physical (row, c) -> read addr XORs the same.
template <int OUTMODE>
__device__ __forceinline__
void gemm_tile(const short* __restrict__ A, int lda,
               const short* __restrict__ Bt, int ldb,
               void* __restrict__ Cout, int ldc, int K,
               int bx, int by, float scale, char* smem) {
    const int tid = threadIdx.x;
    const int wave = tid >> 6, lane = tid & 63;
    const int quad = lane >> 4, ml = lane & 15;
    const int m0 = by * 128, n0 = bx * 128;
    const int wm0 = (wave >> 1) * 64, wn0 = (wave & 1) * 64;
    const int rl = lane >> 3;            // row within an 8-row group (0..7)
    const int ch = lane & 7;             // 16B chunk within 128B row (0..7)
    const int sch = ch ^ rl;             // source-swizzled chunk (involution)

    f32x4 acc[4][4];
    #pragma unroll
    for (int i = 0; i < 4; ++i)
        #pragma unroll
        for (int j = 0; j < 4; ++j) {
            acc[i][j][0] = 0.f; acc[i][j][1] = 0.f;
            acc[i][j][2] = 0.f; acc[i][j][3] = 0.f;
        }

    // Stage A[128x64] + B[128x64] bf16 into sbuf. 8 gl_lds per thread; each
    // instr: 8 rows x 128B (full cache lines). r&7 == rl (group base mult. 8)
    // so the global chunk ch^rl lands at physical chunk ch -> read XOR row&7.
    auto STAGE = [&](char* sbuf, int kt) {
        #pragma unroll
        for (int j = 0; j < 4; ++j) {
            const int r = (wave * 4 + j) * 8 + rl;
            gl_lds16(A + (size_t)(m0 + r) * lda + kt + sch * 8,
                     sbuf + (wave * 4 + j) * 1024 + lane * 16);
        }
        #pragma unroll
        for (int j = 0; j < 4; ++j) {
            const int r = (wave * 4 + j) * 8 + rl;
            gl_lds16(Bt + (size_t)(n0 + r) * ldb + kt + sch * 8,
                     sbuf + 16384 + (wave * 4 + j) * 1024 + lane * 16);
        }
    };

    const int nt = K >> 6;               // >= 4 at every call site
    STAGE(smem, 0);
    __syncthreads();                     // drain vmcnt(0): buf0 ready

    for (int t = 0; t < nt; ++t) {
        char* sbuf = smem + (t & 1) * 32768;
        if (t + 1 < nt)
            STAGE(smem + ((t + 1) & 1) * 32768, (t + 1) * 64);  // prefetch

        const short* sA = (const short*)sbuf;
        const short* sB = (const short*)(sbuf + 16384);
        #pragma unroll
        for (int kk = 0; kk < 2; ++kk) {
            short8 af[4], bfr[4];
            #pragma unroll
            for (int mt = 0; mt < 4; ++mt) {
                const int row = wm0 + mt * 16 + ml;
                af[mt] = *(const short8*)(sA + row * 64 +
                                          (((kk << 2) + quad) ^ (row & 7)) * 8);
            }
            #pragma unroll
            for (int nt2 = 0; nt2 < 4; ++nt2) {
                const int row = wn0 + nt2 * 16 + ml;
                bfr[nt2] = *(const short8*)(sB + row * 64 +
                                            (((kk << 2) + quad) ^ (row & 7)) * 8);
            }
            #pragma unroll
            for (int mt = 0; mt < 4; ++mt)
                #pragma unroll
                for (int nt2 = 0; nt2 < 4; ++nt2)
                    acc[mt][nt2] = __builtin_amdgcn_mfma_f32_16x16x32_bf16(
                        af[mt], bfr[nt2], acc[mt][nt2], 0, 0, 0);
        }
        __syncthreads();  // next buf ready; all waves done reading sbuf
    }

    // C/D layout: col = lane&15, row = quad*4 + reg
    #pragma unroll
    for (int mt = 0; mt < 4; ++mt)
        #pragma unroll
        for (int nt2 = 0; nt2 < 4; ++nt2) {
            const int col = n0 + wn0 + nt2 * 16 + ml;
            #pragma unroll
            for (int r = 0; r < 4; ++r) {
                const int row = m0 + wm0 + mt * 16 + quad * 4 + r;
                float v = acc[mt][nt2][r];
                if (OUTMODE == 2) v *= scale;
                if (OUTMODE == 0)
                    ((float*)Cout)[(size_t)row * ldc + col] = v;
                else
                    ((short*)Cout)[(size_t)row * ldc + col] = f2bf(v);
            }
        }
}

// T1 bijective XCD swizzle for 512-block grids (512 % 8 == 0):
// block i runs on XCD i%8; give each XCD a contiguous tile chunk.
__device__ __forceinline__ int xcd_swz512(int b) {
    return (b & 7) * 64 + (b >> 3);
}

// stage_kv: kvt[2048,4096] = w23t @ yb^T : m-tiles 16, n-tiles 32. 512 blocks.
__global__ __launch_bounds__(256)
void stage_kv(const short* __restrict__ yb, const short* __restrict__ w23t,
              short* __restrict__ kvt) {
    __shared__ char smem[65536];
    const int b = xcd_swz512(blockIdx.x);
    gemm_tile<1>(w23t, 512, yb, 512, kvt, 4096, 512,
                 b & 31, b >> 5, 1.f, smem);
}

// build_u: grid (16,8); Ut tile (s,h) = scale * V_rows @ K_rows^T, K=256.
__global__ __launch_bounds__(256)
void build_u(const short* __restrict__ kvt, const float* __restrict__ cw,
             short* __restrict__ Ut) {
    __shared__ char smem[65536];
    const int s = blockIdx.x, h = blockIdx.y;
    const float scale = cw[h] * (0.08838834764831845f / 256.0f);
    gemm_tile<2>(kvt + (size_t)(1024 + h * 128) * 4096 + s * 256, 4096,  // V
                 kvt + (size_t)(h * 128) * 4096 + s * 256, 4096,         // K
                 Ut + (size_t)(s * 128) * 1024 + h * 128, 1024, 256,
                 0, 0, scale, smem);
}

// build_m: M[2048,512] = Ut @ W1 (Bt = w1b row-major [512,1024]), K=1024.
// grid (4,16) = 64 blocks.
__global__ __launch_bounds__(256)
void build_m(const short* __restrict__ Ut, const short* __restrict__ w1b,
             short* __restrict__ M) {
    __shared__ char smem[65536];
    gemm_tile<1>(Ut, 1024, w1b, 1024, M, 512, 1024,
                 blockIdx.x, blockIdx.y, 1.f, smem);
}

// out[4096,2048] = xb @ M^T, fp32, K=512. 512 blocks (XCD-swizzled).
__global__ __launch_bounds__(256)
void gemm_out(const short* __restrict__ xb, const short* __restrict__ M,
              float* __restrict__ out) {
    __shared__ char smem[65536];
    const int b = xcd_swz512(blockIdx.x);
    gemm_tile<0>(xb, 512, M, 512, out, 2048, 512,
                 b & 15, b >> 4, 1.f, smem);
}

extern "C" void kernel_launch(void* const* d_in, const int* in_sizes, int n_in,
                              void* d_out, int out_size, void* d_ws, size_t ws_size,
                              hipStream_t stream) {
    const float* x  = (const float*)d_in[0];  // [4096, 512]
    const float* y  = (const float*)d_in[1];  // [4096, 512]
    const float* W1 = (const float*)d_in[2];  // [512, 1024]
    const float* W2 = (const float*)d_in[3];
    const float* W3 = (const float*)d_in[4];
    const float* cw = (const float*)d_in[5];  // [8]
    float* out = (float*)d_out;               // [4096, 16, 128]

    short* xb   = (short*)d_ws;                       // 4096*512
    short* yb   = xb   + (size_t)4096 * 512;          // 4096*512
    short* w23t = yb   + (size_t)4096 * 512;          // 2048*512 (transposed)
    short* w1b  = w23t + (size_t)2048 * 512;          // 512*1024 (row-major)
    short* kvt  = w1b  + (size_t)512 * 1024;          // 2048*4096
    short* Ut   = kvt  + (size_t)2048 * 4096;         // 2048*1024
    short* M    = Ut   + (size_t)2048 * 1024;         // 2048*512

    prep<<<3328, 256, 0, stream>>>(x, y, W1, W2, W3, xb, yb, w1b, w23t);
    stage_kv<<<512, 256, 0, stream>>>(yb, w23t, kvt);
    build_u<<<dim3(16, 8), 256, 0, stream>>>(kvt, cw, Ut);
    build_m<<<dim3(4, 16), 256, 0, stream>>>(Ut, w1b, M);
    gemm_out<<<512, 256, 0, stream>>>(xb, M, out);
}